// Round 2
// baseline (94.122 us; speedup 1.0000x reference)
//
#include <hip/hip_runtime.h>
#include <hip/hip_cooperative_groups.h>

namespace cg = cooperative_groups;

// PackedStdScaler: grouped (sample_id, variate_id) masked mean/std over (B,S,D)
// B=4, S=2048, D=128; ids in [0,8) -> 64 groups/batch.
//
// Lesson from rounds 0/1: the 256MiB ws re-poison fill (~41.3us @ 81% HBM peak)
// is an immovable floor in the timed window; above-floor cost was 24.9us for
// 1 node vs 29.6us for 3 nodes -> per-node overhead dominates (~5-8us/node).
// This version: ONE cooperative kernel, init-free (no memset node).
//   Phase A: thread t of block blk owns row blk*128+t; reads full row
//            (32x float4 + mask, unrolled), f64 register accumulation,
//            NO cross-lane reduce; 3 LDS atomics into per-block group slots.
//   Export:  192-double block partial -> ws (agent atomic stores; every byte
//            consumed is written this launch -> poison-proof).
//   grid.sync()
//   Phase B: block reduces its batch's 16 partials (agent atomic loads,
//            cross-XCD safe), computes per-group loc/scale, scatters its rows.

#define BB 4
#define SS 2048
#define DD 128
#define NROW (BB * SS)     // 8192
#define NG 64              // groups per batch
#define BPB 16             // blocks per batch
#define NBLK (BB * BPB)    // 64 blocks
#define NT 128             // threads per block == rows per block

__device__ __forceinline__ void acc1(float t, int m, int& c, double& s1, double& s2) {
    const double v = m ? (double)t : 0.0;   // branchless: cndmask, no divergence
    s1 += v;
    s2 = fma(v, v, s2);
    c += m ? 1 : 0;
}

__global__ __launch_bounds__(NT) void pss_fused(
    const float* __restrict__ target,
    const unsigned* __restrict__ mask_raw,   // raw words of observed_mask
    const int* __restrict__ sample_id,
    const int* __restrict__ variate_id,
    float* __restrict__ out,                 // [0,NROW): loc, [NROW,2*NROW): scale
    double* __restrict__ ws)                 // [NBLK][NG][3] block partials
{
    const int tid   = threadIdx.x;
    const int blk   = blockIdx.x;
    const int batch = blk >> 4;              // 16 blocks per batch

    __shared__ int    s_cnt[NG];
    __shared__ double s_s1[NG], s_s2[NG];
    __shared__ double s_fin[NG * 3];
    __shared__ float  s_ls[NG][2];
    __shared__ int    s_mflag;

    if (tid < NG) { s_cnt[tid] = 0; s_s1[tid] = 0.0; s_s2[tid] = 0.0; }
    // mask dtype detection: byte-bool buffer => some of first 64 words > 1
    if (tid < 64) {
        const unsigned long long bal = __ballot(mask_raw[tid] > 1u);
        if (tid == 0) s_mflag = (bal != 0ull) ? 1 : 0;
    }
    __syncthreads();
    const bool bytemask = (s_mflag != 0);

    // ---- Phase A: per-thread full-row accumulate (no cross-lane reduce) ----
    const int srow = blk * NT + tid;         // global row in [0, 8192)
    const int key  = (sample_id[srow] * 8 + variate_id[srow]) & 63; // clamp-safe
    const size_t off = (size_t)srow * DD;

    int c = 0; double s1 = 0.0, s2 = 0.0;
    const float4* tp = (const float4*)(target + off);   // 32 x float4 per row
    if (bytemask) {
        const uint4* mp = (const uint4*)((const unsigned char*)mask_raw + off); // 8 x uint4
        #pragma unroll
        for (int ch = 0; ch < 8; ++ch) {
            const uint4 mv = mp[ch];
            const unsigned mw[4] = { mv.x, mv.y, mv.z, mv.w };
            #pragma unroll
            for (int w = 0; w < 4; ++w) {
                const float4 t = tp[ch * 4 + w];
                const unsigned m = mw[w];
                acc1(t.x, (int)(m         & 0xffu), c, s1, s2);
                acc1(t.y, (int)((m >> 8)  & 0xffu), c, s1, s2);
                acc1(t.z, (int)((m >> 16) & 0xffu), c, s1, s2);
                acc1(t.w, (int)((m >> 24) & 0xffu), c, s1, s2);
            }
        }
    } else {
        const uint4* mp = (const uint4*)((const unsigned*)mask_raw + off);      // 32 x uint4
        #pragma unroll
        for (int ch = 0; ch < 8; ++ch) {
            #pragma unroll
            for (int w = 0; w < 4; ++w) {
                const float4 t = tp[ch * 4 + w];
                const uint4  m = mp[ch * 4 + w];
                acc1(t.x, (int)m.x, c, s1, s2);
                acc1(t.y, (int)m.y, c, s1, s2);
                acc1(t.z, (int)m.z, c, s1, s2);
                acc1(t.w, (int)m.w, c, s1, s2);
            }
        }
    }

    // low-contention LDS accumulation (~2 rows/key/block on average)
    atomicAdd(&s_cnt[key], c);
    unsafeAtomicAdd(&s_s1[key], s1);
    unsafeAtomicAdd(&s_s2[key], s2);
    __syncthreads();

    // ---- export block partial (agent scope -> coherent across XCDs) ----
    double* pw = ws + (size_t)blk * (NG * 3);
    if (tid < NG) {
        __hip_atomic_store(pw + tid * 3 + 0, (double)s_cnt[tid],
                           __ATOMIC_RELAXED, __HIP_MEMORY_SCOPE_AGENT);
        __hip_atomic_store(pw + tid * 3 + 1, s_s1[tid],
                           __ATOMIC_RELAXED, __HIP_MEMORY_SCOPE_AGENT);
        __hip_atomic_store(pw + tid * 3 + 2, s_s2[tid],
                           __ATOMIC_RELAXED, __HIP_MEMORY_SCOPE_AGENT);
    }

    cg::this_grid().sync();

    // ---- Phase B: reduce this batch's 16 partials, finalize, scatter ----
    double* base = ws + (size_t)(batch * BPB) * (NG * 3);
    for (int t = tid; t < NG * 3; t += NT) {
        double a = 0.0;
        #pragma unroll
        for (int j = 0; j < BPB; ++j)
            a += __hip_atomic_load(base + (size_t)j * (NG * 3) + t,
                                   __ATOMIC_RELAXED, __HIP_MEMORY_SCOPE_AGENT);
        s_fin[t] = a;
    }
    __syncthreads();

    if (tid < NG) {
        const double cnt = s_fin[tid * 3 + 0];
        const double gs  = s_fin[tid * 3 + 1];
        const double gss = s_fin[tid * 3 + 2];
        // safe_div semantics: den==0 -> divide by 1
        const double loc = gs / (cnt == 0.0 ? 1.0 : cnt);
        double varnum = gss - 2.0 * loc * gs + loc * loc * cnt; // sum((t-loc)^2*obs)
        if (varnum < 0.0) varnum = 0.0;                         // fp cancellation guard
        const double den = cnt - 1.0;                           // CORRECTION = 1
        double var = varnum / (den == 0.0 ? 1.0 : den);
        if (var < 0.0) var = 0.0;
        s_ls[tid][0] = (float)loc;
        s_ls[tid][1] = (float)sqrt(var + 1e-5);                 // MINIMUM_SCALE
    }
    __syncthreads();

    float locf, scalef;
    if (key < 8) { locf = 0.f; scalef = 1.f; }                  // sample_id==0 padding
    else         { locf = s_ls[key][0]; scalef = s_ls[key][1]; }
    out[srow]        = locf;
    out[NROW + srow] = scalef;
}

extern "C" void kernel_launch(void* const* d_in, const int* in_sizes, int n_in,
                              void* d_out, int out_size, void* d_ws, size_t ws_size,
                              hipStream_t stream) {
    const float*    target = (const float*)d_in[0];
    const unsigned* mask   = (const unsigned*)d_in[1];
    const int*      sid    = (const int*)d_in[2];
    const int*      vid    = (const int*)d_in[3];
    float*          out    = (float*)d_out;
    double*         ws     = (double*)d_ws;

    void* args[] = { (void*)&target, (void*)&mask, (void*)&sid, (void*)&vid,
                     (void*)&out, (void*)&ws };
    hipLaunchCooperativeKernel((const void*)pss_fused, dim3(NBLK), dim3(NT),
                               args, 0, stream);
}

// Round 4
// 65.627 us; speedup vs baseline: 1.4342x; 1.4342x over previous
//
#include <hip/hip_runtime.h>

// PackedStdScaler: grouped (sample_id, variate_id) masked mean/std over (B,S,D)
// B=4, S=2048, D=128; ids in [0,8) -> 64 groups/batch.
//
// Ledger (above the ~41.3us ws re-poison fill floor, F=fixed, n=per-node):
//   R0: 1 node, F+n+K0 = 24.9 | R1: 3 nodes = 29.6 | R2: cooperative = 52.8
//   R3: persistent-state ticket design -> container death. Lesson: stateless.
// => ONE regular node, stateless block-per-(batch,group), and shrink K0.
//
// Fixes vs R0's kernel (the 66.2us best):
//  1. mask-dtype detect via one wave-0 ballot (R0: 512-thread same-address
//     LDS atomicOr ~ multi-us serialize -- the main cost).
//  2. NT 512->1024: 16 waves -> ~2 dependent row-read chains per wave
//     instead of 4 (each chain ~700cy HBM latency).
//  3. Parallel cross-wave reduce (shuffle over 16 lane-partials) instead of
//     serial tid==0 loop.
// Math/compaction/write-back identical to R0 (verified absmax 0.0).

#define BB 4
#define SS 2048
#define DD 128
#define NROW (BB * SS)
#define NG 64
#define NT 1024
#define NW (NT / 64)         // 16 waves

__global__ __launch_bounds__(NT) void pss_kernel(
    const float* __restrict__ target,
    const unsigned* __restrict__ mask_raw,   // raw words of observed_mask
    const int* __restrict__ sample_id,
    const int* __restrict__ variate_id,
    float* __restrict__ out)                 // [0,NROW): loc, [NROW,2*NROW): scale
{
    const int b    = blockIdx.y;
    const int g    = blockIdx.x;
    const int tid  = threadIdx.x;
    const int lane = tid & 63;
    const int wave = tid >> 6;

    __shared__ unsigned short rows[SS];
    __shared__ int nrows;
    __shared__ int s_mflag;
    __shared__ double red[NW][3];
    __shared__ float bcast[2];

    if (tid == 0) nrows = 0;
    // mask dtype detection: byte-bool buffer => some of first 64 words > 1.
    // One wave, one ballot, zero atomics.
    if (tid < 64) {
        const unsigned long long bal = __ballot(mask_raw[tid] > 1u);
        if (tid == 0) s_mflag = (bal != 0ull) ? 1 : 0;
    }
    __syncthreads();
    const bool bytemask = (s_mflag != 0);

    // --- gather rows of group g (batch b): int2 id loads, ballot compaction.
    // NT*2 == SS: one iteration covers all ids.
    {
        const int2 sv = ((const int2*)(sample_id + b * SS))[tid];
        const int2 vv = ((const int2*)(variate_id + b * SS))[tid];
        const int keys[2] = { sv.x * 8 + vv.x, sv.y * 8 + vv.y };
        #pragma unroll
        for (int j = 0; j < 2; j++) {
            const bool hit = (keys[j] == g);
            const unsigned long long bal = __ballot(hit);
            if (bal) {
                int base;
                if (lane == 0) base = atomicAdd(&nrows, __popcll(bal));
                base = __shfl(base, 0, 64);
                if (hit) {
                    const int pre = __popcll(bal & ((1ull << lane) - 1ull));
                    rows[base + pre] = (unsigned short)(2 * tid + j);
                }
            }
        }
    }
    __syncthreads();
    const int M = nrows;

    // --- accumulate cnt / sum / sumsq over group's observed entries.
    // One wave per row: 64 lanes x float2 = full 128-wide row. ~2 rows/wave.
    float  c  = 0.f;
    double s1 = 0.0, s2 = 0.0;
    for (int i = wave; i < M; i += NW) {
        const int s = rows[i];
        const size_t rowoff = ((size_t)(b * SS + s)) * DD;
        const float2 tv = ((const float2*)(target + rowoff))[lane];
        int m0, m1;
        if (bytemask) {
            const uchar2 mv =
                ((const uchar2*)(((const unsigned char*)mask_raw) + rowoff))[lane];
            m0 = mv.x; m1 = mv.y;
        } else {
            const int2 mv =
                ((const int2*)(((const int*)mask_raw) + rowoff))[lane];
            m0 = mv.x; m1 = mv.y;
        }
        if (m0) { c += 1.f; s1 += (double)tv.x; s2 += (double)tv.x * (double)tv.x; }
        if (m1) { c += 1.f; s1 += (double)tv.y; s2 += (double)tv.y * (double)tv.y; }
    }

    // --- wave reduce (64 lanes), then cross-wave via LDS + wave-0 shuffle
    for (int off = 32; off > 0; off >>= 1) {
        c  += __shfl_down(c,  off, 64);
        s1 += __shfl_down(s1, off, 64);
        s2 += __shfl_down(s2, off, 64);
    }
    if (lane == 0) { red[wave][0] = (double)c; red[wave][1] = s1; red[wave][2] = s2; }
    __syncthreads();

    if (wave == 0) {
        double a0 = (lane < NW) ? red[lane][0] : 0.0;
        double a1 = (lane < NW) ? red[lane][1] : 0.0;
        double a2 = (lane < NW) ? red[lane][2] : 0.0;
        for (int off = 8; off > 0; off >>= 1) {
            a0 += __shfl_down(a0, off, 64);
            a1 += __shfl_down(a1, off, 64);
            a2 += __shfl_down(a2, off, 64);
        }
        if (lane == 0) {
            const double cnt = a0, gs = a1, gss = a2;
            // safe_div semantics: den==0 -> divide by 1
            const double loc = gs / (cnt == 0.0 ? 1.0 : cnt);
            double varnum = gss - 2.0 * loc * gs + loc * loc * cnt; // sum((t-loc)^2*obs)
            if (varnum < 0.0) varnum = 0.0;                         // cancellation guard
            const double den = cnt - 1.0;                           // CORRECTION = 1
            double var = varnum / (den == 0.0 ? 1.0 : den);
            if (var < 0.0) var = 0.0;
            float locf   = (float)loc;
            float scalef = (float)sqrt(var + 1e-5);                 // MINIMUM_SCALE
            if (g < 8) { locf = 0.f; scalef = 1.f; }                // sample_id==0 pad
            bcast[0] = locf; bcast[1] = scalef;
        }
    }
    __syncthreads();

    const float locf = bcast[0], scalef = bcast[1];
    for (int i = tid; i < M; i += NT) {
        const int s = rows[i];
        out[b * SS + s]        = locf;
        out[NROW + b * SS + s] = scalef;
    }
}

extern "C" void kernel_launch(void* const* d_in, const int* in_sizes, int n_in,
                              void* d_out, int out_size, void* d_ws, size_t ws_size,
                              hipStream_t stream) {
    const float*    target = (const float*)d_in[0];
    const unsigned* mask   = (const unsigned*)d_in[1];
    const int*      sid    = (const int*)d_in[2];
    const int*      vid    = (const int*)d_in[3];
    float*          out    = (float*)d_out;

    dim3 grid(NG, BB);
    hipLaunchKernelGGL(pss_kernel, grid, dim3(NT), 0, stream,
                       target, mask, sid, vid, out);
}